// Round 1
// baseline (2553.225 us; speedup 1.0000x reference)
//
#include <hip/hip_runtime.h>

#define USER_COUNT 200000
#define ITEM_COUNT 100000
#define N_NODES    300000   // USER_COUNT + ITEM_COUNT
#define EMB        64
#define BATCH      4096

// ---------------------------------------------------------------------------
// Build row_ptr from the sorted COO row array.
// ptr[r] = first index i with row[i] >= r ; ptr[N_NODES] = nnz.
// Rows are ~uniform-random (avg 32 nnz/row), so gaps between consecutive
// distinct rows are tiny -> the per-thread fill loop is short.
// ---------------------------------------------------------------------------
__global__ void build_row_ptr(const int* __restrict__ row,
                              int* __restrict__ ptr, int nnz) {
    int i = blockIdx.x * blockDim.x + threadIdx.x;
    if (i >= nnz) return;
    int r  = row[i];
    int rp = (i == 0) ? -1 : row[i - 1];
    for (int rr = rp + 1; rr <= r; ++rr) ptr[rr] = i;
    if (i == nnz - 1) {
        for (int rr = r + 1; rr <= N_NODES; ++rr) ptr[rr] = nnz;
    }
}

// ---------------------------------------------------------------------------
// SpMM: y[r] = sum_j val[j] * x[col[j]]  over the segment ptr[r]..ptr[r+1].
// One 64-lane wave per row; lane = embedding dim. x is addressed through a
// virtual concat: col < USER_COUNT -> xu + col*EMB ; else xi + (col-UC)*EMB.
// For later layers pass xu = h, xi = h + USER_COUNT*EMB (same formula).
// ---------------------------------------------------------------------------
__global__ __launch_bounds__(256) void spmm_kernel(
        const float* __restrict__ xu, const float* __restrict__ xi,
        const int*   __restrict__ col, const float* __restrict__ val,
        const int*   __restrict__ ptr, float* __restrict__ y) {
    int wave = (int)((blockIdx.x * blockDim.x + threadIdx.x) >> 6);
    int lane = threadIdx.x & 63;
    if (wave >= N_NODES) return;
    int p0 = ptr[wave];
    int p1 = ptr[wave + 1];
    float acc = 0.0f;
    for (int j = p0; j < p1; ++j) {
        int   c = col[j];
        float v = val[j];
        const float* base = (c < USER_COUNT)
                          ? (xu + (size_t)c * EMB)
                          : (xi + (size_t)(c - USER_COUNT) * EMB);
        acc += v * base[lane];
    }
    y[(size_t)wave * EMB + lane] = acc;
}

// ---------------------------------------------------------------------------
// Gather the 8192 selected rows (4096 users, then 4096 items), scale by 1/4,
// and write (ADD=false) or accumulate (ADD=true) into out.
// out layout: [users(4096) x 64][items(4096) x 64], flat f32.
// ---------------------------------------------------------------------------
template <bool ADD>
__global__ void gather_kernel(const float* __restrict__ xu,
                              const float* __restrict__ xi,
                              const int* __restrict__ users,
                              const int* __restrict__ items,
                              float* __restrict__ out) {
    int tid = blockIdx.x * blockDim.x + threadIdx.x;
    if (tid >= 2 * BATCH * EMB) return;
    int b = tid >> 6;   // row in batch
    int e = tid & 63;   // emb dim
    float s;
    if (b < BATCH) {
        int u = users[b];
        s = xu[(size_t)u * EMB + e];
    } else {
        int it = items[b - BATCH];
        s = xi[(size_t)it * EMB + e];
    }
    float v = 0.25f * s;   // 1 / (N_LAYERS + 1)
    if (ADD) out[tid] += v;
    else     out[tid] = v;
}

extern "C" void kernel_launch(void* const* d_in, const int* in_sizes, int n_in,
                              void* d_out, int out_size, void* d_ws, size_t ws_size,
                              hipStream_t stream) {
    const float* user_emb = (const float*)d_in[0];
    const float* item_emb = (const float*)d_in[1];
    const int*   adj_row  = (const int*)d_in[2];
    const int*   adj_col  = (const int*)d_in[3];
    const float* adj_val  = (const float*)d_in[4];
    const int*   users    = (const int*)d_in[5];
    const int*   items    = (const int*)d_in[6];
    float*       out      = (float*)d_out;
    const int    nnz      = in_sizes[2];

    char* ws = (char*)d_ws;
    const size_t hbytes = (size_t)N_NODES * EMB * sizeof(float); // 76.8 MB
    float* hA  = (float*)(ws);
    float* hB  = (float*)(ws + hbytes);
    int*   ptr = (int*)  (ws + 2 * hbytes);

    // 1) row_ptr from sorted rows
    build_row_ptr<<<(nnz + 255) / 256, 256, 0, stream>>>(adj_row, ptr, nnz);

    // 2) out = 0.25 * ego[selected]   (layer-0 term; WRITE, since out is poisoned)
    const int gthreads = 2 * BATCH * EMB;
    gather_kernel<false><<<(gthreads + 255) / 256, 256, 0, stream>>>(
        user_emb, item_emb, users, items, out);

    const int spmm_blocks = (N_NODES + 3) / 4;  // 4 waves (rows) per 256-thread block

    // 3) h1 = A * ego   (reads inputs via virtual concat)
    spmm_kernel<<<spmm_blocks, 256, 0, stream>>>(
        user_emb, item_emb, adj_col, adj_val, ptr, hA);
    gather_kernel<true><<<(gthreads + 255) / 256, 256, 0, stream>>>(
        hA, hA + (size_t)USER_COUNT * EMB, users, items, out);

    // 4) h2 = A * h1
    spmm_kernel<<<spmm_blocks, 256, 0, stream>>>(
        hA, hA + (size_t)USER_COUNT * EMB, adj_col, adj_val, ptr, hB);
    gather_kernel<true><<<(gthreads + 255) / 256, 256, 0, stream>>>(
        hB, hB + (size_t)USER_COUNT * EMB, users, items, out);

    // 5) h3 = A * h2
    spmm_kernel<<<spmm_blocks, 256, 0, stream>>>(
        hB, hB + (size_t)USER_COUNT * EMB, adj_col, adj_val, ptr, hA);
    gather_kernel<true><<<(gthreads + 255) / 256, 256, 0, stream>>>(
        hA, hA + (size_t)USER_COUNT * EMB, users, items, out);
}

// Round 2
// 1026.648 us; speedup vs baseline: 2.4870x; 2.4870x over previous
//
#include <hip/hip_runtime.h>

#define USER_COUNT 200000
#define ITEM_COUNT 100000
#define N_NODES    300000   // USER_COUNT + ITEM_COUNT
#define EMB        64
#define BATCH      4096

// ---------------------------------------------------------------------------
// Build row_ptr from the sorted COO row array.
// ptr[r] = first index i with row[i] >= r ; ptr[N_NODES] = nnz.
// ---------------------------------------------------------------------------
__global__ void build_row_ptr(const int* __restrict__ row,
                              int* __restrict__ ptr, int nnz) {
    int i = blockIdx.x * blockDim.x + threadIdx.x;
    if (i >= nnz) return;
    int r  = row[i];
    int rp = (i == 0) ? -1 : row[i - 1];
    for (int rr = rp + 1; rr <= r; ++rr) ptr[rr] = i;
    if (i == nnz - 1) {
        for (int rr = r + 1; rr <= N_NODES; ++rr) ptr[rr] = nnz;
    }
}

// ---------------------------------------------------------------------------
// SpMM, CSR-vector style: one 64-lane wave per row.
//   e = lane>>4   : edge slot (4 edges processed concurrently)
//   d = (lane&15)*4 : float4 chunk of the 64-dim embedding
// Unrolled x2 -> 8 independent 256B gathers in flight per wave.
// Epilogue: shfl_xor(16),(32) butterfly sums the 4 edge-slot partials,
// then edge-slot 0 (lanes 0..15) stores the row as float4.
// ---------------------------------------------------------------------------
__global__ __launch_bounds__(256) void spmm_kernel(
        const float* __restrict__ xu, const float* __restrict__ xi,
        const int*   __restrict__ col, const float* __restrict__ val,
        const int*   __restrict__ ptr, float* __restrict__ y) {
    int wave = (int)((blockIdx.x * blockDim.x + threadIdx.x) >> 6);
    int lane = threadIdx.x & 63;
    if (wave >= N_NODES) return;
    int e = lane >> 4;          // 0..3
    int d = (lane & 15) << 2;   // 0,4,...,60

    int p0 = ptr[wave];
    int p1 = ptr[wave + 1];

    float4 acc0 = {0.f, 0.f, 0.f, 0.f};
    float4 acc1 = {0.f, 0.f, 0.f, 0.f};

    int j = p0 + e;
    // main loop: this edge-slot handles edges j and j+4 per iteration
    for (; j + 4 < p1; j += 8) {
        int   c0 = col[j];     float v0 = val[j];
        int   c1 = col[j + 4]; float v1 = val[j + 4];
        const float* b0 = (c0 < USER_COUNT)
                        ? (xu + (size_t)c0 * EMB)
                        : (xi + (size_t)(c0 - USER_COUNT) * EMB);
        const float* b1 = (c1 < USER_COUNT)
                        ? (xu + (size_t)c1 * EMB)
                        : (xi + (size_t)(c1 - USER_COUNT) * EMB);
        float4 x0 = *(const float4*)(b0 + d);
        float4 x1 = *(const float4*)(b1 + d);
        acc0.x += v0 * x0.x; acc0.y += v0 * x0.y;
        acc0.z += v0 * x0.z; acc0.w += v0 * x0.w;
        acc1.x += v1 * x1.x; acc1.y += v1 * x1.y;
        acc1.z += v1 * x1.z; acc1.w += v1 * x1.w;
    }
    if (j < p1) {
        int   c = col[j]; float v = val[j];
        const float* b = (c < USER_COUNT)
                       ? (xu + (size_t)c * EMB)
                       : (xi + (size_t)(c - USER_COUNT) * EMB);
        float4 x = *(const float4*)(b + d);
        acc0.x += v * x.x; acc0.y += v * x.y;
        acc0.z += v * x.z; acc0.w += v * x.w;
    }

    acc0.x += acc1.x; acc0.y += acc1.y; acc0.z += acc1.z; acc0.w += acc1.w;

    // combine the 4 edge slots (groups of 16 lanes)
    acc0.x += __shfl_xor(acc0.x, 16, 64);
    acc0.y += __shfl_xor(acc0.y, 16, 64);
    acc0.z += __shfl_xor(acc0.z, 16, 64);
    acc0.w += __shfl_xor(acc0.w, 16, 64);
    acc0.x += __shfl_xor(acc0.x, 32, 64);
    acc0.y += __shfl_xor(acc0.y, 32, 64);
    acc0.z += __shfl_xor(acc0.z, 32, 64);
    acc0.w += __shfl_xor(acc0.w, 32, 64);

    if (e == 0) {
        *(float4*)(y + (size_t)wave * EMB + d) = acc0;
    }
}

// ---------------------------------------------------------------------------
// Gather 8192 selected rows (4096 users, 4096 items), scale by 1/4,
// write (ADD=false) or accumulate (ADD=true) into out.
// ---------------------------------------------------------------------------
template <bool ADD>
__global__ void gather_kernel(const float* __restrict__ xu,
                              const float* __restrict__ xi,
                              const int* __restrict__ users,
                              const int* __restrict__ items,
                              float* __restrict__ out) {
    int tid = blockIdx.x * blockDim.x + threadIdx.x;
    if (tid >= 2 * BATCH * (EMB / 4)) return;
    int b = tid >> 4;          // row in batch (0..8191)
    int e = (tid & 15) << 2;   // float4 chunk
    const float* src;
    if (b < BATCH) {
        int u = users[b];
        src = xu + (size_t)u * EMB + e;
    } else {
        int it = items[b - BATCH];
        src = xi + (size_t)it * EMB + e;
    }
    float4 s = *(const float4*)src;
    float4* o = (float4*)(out + (size_t)b * EMB + e);
    if (ADD) {
        float4 cur = *o;
        cur.x += 0.25f * s.x; cur.y += 0.25f * s.y;
        cur.z += 0.25f * s.z; cur.w += 0.25f * s.w;
        *o = cur;
    } else {
        float4 v = {0.25f * s.x, 0.25f * s.y, 0.25f * s.z, 0.25f * s.w};
        *o = v;
    }
}

extern "C" void kernel_launch(void* const* d_in, const int* in_sizes, int n_in,
                              void* d_out, int out_size, void* d_ws, size_t ws_size,
                              hipStream_t stream) {
    const float* user_emb = (const float*)d_in[0];
    const float* item_emb = (const float*)d_in[1];
    const int*   adj_row  = (const int*)d_in[2];
    const int*   adj_col  = (const int*)d_in[3];
    const float* adj_val  = (const float*)d_in[4];
    const int*   users    = (const int*)d_in[5];
    const int*   items    = (const int*)d_in[6];
    float*       out      = (float*)d_out;
    const int    nnz      = in_sizes[2];

    char* ws = (char*)d_ws;
    const size_t hbytes = (size_t)N_NODES * EMB * sizeof(float); // 76.8 MB
    float* hA  = (float*)(ws);
    float* hB  = (float*)(ws + hbytes);
    int*   ptr = (int*)  (ws + 2 * hbytes);

    // 1) row_ptr from sorted rows
    build_row_ptr<<<(nnz + 255) / 256, 256, 0, stream>>>(adj_row, ptr, nnz);

    // 2) out = 0.25 * ego[selected]
    const int gthreads = 2 * BATCH * (EMB / 4);
    gather_kernel<false><<<(gthreads + 255) / 256, 256, 0, stream>>>(
        user_emb, item_emb, users, items, out);

    const int spmm_blocks = (N_NODES + 3) / 4;  // 4 waves (rows) per block

    // 3) h1 = A * ego
    spmm_kernel<<<spmm_blocks, 256, 0, stream>>>(
        user_emb, item_emb, adj_col, adj_val, ptr, hA);
    gather_kernel<true><<<(gthreads + 255) / 256, 256, 0, stream>>>(
        hA, hA + (size_t)USER_COUNT * EMB, users, items, out);

    // 4) h2 = A * h1
    spmm_kernel<<<spmm_blocks, 256, 0, stream>>>(
        hA, hA + (size_t)USER_COUNT * EMB, adj_col, adj_val, ptr, hB);
    gather_kernel<true><<<(gthreads + 255) / 256, 256, 0, stream>>>(
        hB, hB + (size_t)USER_COUNT * EMB, users, items, out);

    // 5) h3 = A * h2
    spmm_kernel<<<spmm_blocks, 256, 0, stream>>>(
        hB, hB + (size_t)USER_COUNT * EMB, adj_col, adj_val, ptr, hA);
    gather_kernel<true><<<(gthreads + 255) / 256, 256, 0, stream>>>(
        hA, hA + (size_t)USER_COUNT * EMB, users, items, out);
}

// Round 3
// 523.919 us; speedup vs baseline: 4.8733x; 1.9596x over previous
//
#include <hip/hip_runtime.h>

#define USER_COUNT 200000
#define ITEM_COUNT 100000
#define N_NODES    300000   // USER_COUNT + ITEM_COUNT
#define EMB        64
#define BATCH      4096

typedef unsigned int  u32;
typedef unsigned short u16;

static __device__ __forceinline__ float bf2f(u16 h) {
    return __uint_as_float(((u32)h) << 16);
}
static __device__ __forceinline__ u16 f2bf(float f) {   // round-to-nearest-even
    u32 u = __float_as_uint(f);
    u32 r = (u + 0x7FFFu + ((u >> 16) & 1u)) >> 16;
    return (u16)r;
}

// ---------------------------------------------------------------------------
// row_ptr from sorted COO rows. ptr[r] = first i with row[i] >= r.
// ---------------------------------------------------------------------------
__global__ void build_row_ptr(const int* __restrict__ row,
                              int* __restrict__ ptr, int nnz) {
    int i = blockIdx.x * blockDim.x + threadIdx.x;
    if (i >= nnz) return;
    int r  = row[i];
    int rp = (i == 0) ? -1 : row[i - 1];
    for (int rr = rp + 1; rr <= r; ++rr) ptr[rr] = i;
    if (i == nnz - 1) {
        for (int rr = r + 1; rr <= N_NODES; ++rr) ptr[rr] = nnz;
    }
}

// ---------------------------------------------------------------------------
// ego16 = bf16(concat(user_emb, item_emb)); each thread converts 4 elems.
// ---------------------------------------------------------------------------
__global__ void convert_bf16(const float* __restrict__ ue,
                             const float* __restrict__ ie,
                             u16* __restrict__ out16) {
    size_t t = (size_t)blockIdx.x * blockDim.x + threadIdx.x;
    const size_t total = (size_t)N_NODES * EMB / 4;
    if (t >= total) return;
    size_t base = t * 4;
    const size_t ub = (size_t)USER_COUNT * EMB;
    const float* src = (base < ub) ? (ue + base) : (ie + (base - ub));
    float4 v = *(const float4*)src;
    ushort4 o;
    o.x = f2bf(v.x); o.y = f2bf(v.y); o.z = f2bf(v.z); o.w = f2bf(v.w);
    *(ushort4*)(out16 + base) = o;
}

// ---------------------------------------------------------------------------
// Inner gather-FMA: 16-lane group handles one edge; lane covers 4 bf16 dims.
// ---------------------------------------------------------------------------
#define EDGE_FMA(J, ACC)                                              \
    {                                                                 \
        int   c = __builtin_nontemporal_load(col + (J));              \
        float v = __builtin_nontemporal_load(val + (J));              \
        ushort4 h4 = *(const ushort4*)(x + (size_t)c * EMB + d);      \
        ACC.x += v * bf2f(h4.x);                                      \
        ACC.y += v * bf2f(h4.y);                                      \
        ACC.z += v * bf2f(h4.z);                                      \
        ACC.w += v * bf2f(h4.w);                                      \
    }

// ---------------------------------------------------------------------------
// Full SpMM (bf16 in / bf16 out): one wave per row.
//   e = lane>>4 : edge slot (4 concurrent edges); d = (lane&15)*4 dims.
// Unroll x4 -> 16 independent 128B gathers in flight per wave.
// ---------------------------------------------------------------------------
__global__ __launch_bounds__(256) void spmm_bf16(
        const u16* __restrict__ x, const int* __restrict__ col,
        const float* __restrict__ val, const int* __restrict__ ptr,
        u16* __restrict__ y) {
    int wave = (int)((blockIdx.x * blockDim.x + threadIdx.x) >> 6);
    int lane = threadIdx.x & 63;
    if (wave >= N_NODES) return;
    int e = lane >> 4;
    int d = (lane & 15) << 2;

    int p0 = ptr[wave];
    int p1 = ptr[wave + 1];

    float4 a0 = {0,0,0,0}, a1 = {0,0,0,0}, a2 = {0,0,0,0}, a3 = {0,0,0,0};

    int j = p0 + e;
    for (; j + 12 < p1; j += 16) {
        EDGE_FMA(j,      a0);
        EDGE_FMA(j + 4,  a1);
        EDGE_FMA(j + 8,  a2);
        EDGE_FMA(j + 12, a3);
    }
    for (; j < p1; j += 4) EDGE_FMA(j, a0);

    a0.x += a1.x + a2.x + a3.x;
    a0.y += a1.y + a2.y + a3.y;
    a0.z += a1.z + a2.z + a3.z;
    a0.w += a1.w + a2.w + a3.w;

    a0.x += __shfl_xor(a0.x, 16, 64);
    a0.y += __shfl_xor(a0.y, 16, 64);
    a0.z += __shfl_xor(a0.z, 16, 64);
    a0.w += __shfl_xor(a0.w, 16, 64);
    a0.x += __shfl_xor(a0.x, 32, 64);
    a0.y += __shfl_xor(a0.y, 32, 64);
    a0.z += __shfl_xor(a0.z, 32, 64);
    a0.w += __shfl_xor(a0.w, 32, 64);

    if (e == 0) {
        ushort4 o;
        o.x = f2bf(a0.x); o.y = f2bf(a0.y); o.z = f2bf(a0.z); o.w = f2bf(a0.w);
        *(ushort4*)(y + (size_t)wave * EMB + d) = o;
    }
}

// ---------------------------------------------------------------------------
// Layer-3 SpMM restricted to the 8192 selected rows, fused with the output
// accumulation: out[slot] += 0.25 * (A * x)[row(slot)].
// Distinct slots write distinct out rows -> no conflicts even w/ dup nodes.
// ---------------------------------------------------------------------------
__global__ __launch_bounds__(256) void spmm_bf16_sel(
        const u16* __restrict__ x, const int* __restrict__ col,
        const float* __restrict__ val, const int* __restrict__ ptr,
        const int* __restrict__ users, const int* __restrict__ items,
        float* __restrict__ out) {
    int slot = (int)((blockIdx.x * blockDim.x + threadIdx.x) >> 6);
    if (slot >= 2 * BATCH) return;
    int lane = threadIdx.x & 63;
    int e = lane >> 4;
    int d = (lane & 15) << 2;

    int row = (slot < BATCH) ? users[slot] : (items[slot - BATCH] + USER_COUNT);
    int p0 = ptr[row];
    int p1 = ptr[row + 1];

    float4 a0 = {0,0,0,0}, a1 = {0,0,0,0}, a2 = {0,0,0,0}, a3 = {0,0,0,0};

    int j = p0 + e;
    for (; j + 12 < p1; j += 16) {
        EDGE_FMA(j,      a0);
        EDGE_FMA(j + 4,  a1);
        EDGE_FMA(j + 8,  a2);
        EDGE_FMA(j + 12, a3);
    }
    for (; j < p1; j += 4) EDGE_FMA(j, a0);

    a0.x += a1.x + a2.x + a3.x;
    a0.y += a1.y + a2.y + a3.y;
    a0.z += a1.z + a2.z + a3.z;
    a0.w += a1.w + a2.w + a3.w;

    a0.x += __shfl_xor(a0.x, 16, 64);
    a0.y += __shfl_xor(a0.y, 16, 64);
    a0.z += __shfl_xor(a0.z, 16, 64);
    a0.w += __shfl_xor(a0.w, 16, 64);
    a0.x += __shfl_xor(a0.x, 32, 64);
    a0.y += __shfl_xor(a0.y, 32, 64);
    a0.z += __shfl_xor(a0.z, 32, 64);
    a0.w += __shfl_xor(a0.w, 32, 64);

    if (e == 0) {
        float4* o = (float4*)(out + (size_t)slot * EMB + d);
        float4 cur = *o;
        cur.x += 0.25f * a0.x; cur.y += 0.25f * a0.y;
        cur.z += 0.25f * a0.z; cur.w += 0.25f * a0.w;
        *o = cur;
    }
}

// ---------------------------------------------------------------------------
// out = 0.25 * ego[selected]  (from the exact f32 inputs; first write)
// ---------------------------------------------------------------------------
__global__ void gather_f32(const float* __restrict__ xu,
                           const float* __restrict__ xi,
                           const int* __restrict__ users,
                           const int* __restrict__ items,
                           float* __restrict__ out) {
    int tid = blockIdx.x * blockDim.x + threadIdx.x;
    if (tid >= 2 * BATCH * (EMB / 4)) return;
    int b = tid >> 4;
    int e = (tid & 15) << 2;
    const float* src;
    if (b < BATCH) src = xu + (size_t)users[b] * EMB + e;
    else           src = xi + (size_t)items[b - BATCH] * EMB + e;
    float4 s = *(const float4*)src;
    float4 v = {0.25f * s.x, 0.25f * s.y, 0.25f * s.z, 0.25f * s.w};
    *(float4*)(out + (size_t)b * EMB + e) = v;
}

// ---------------------------------------------------------------------------
// out += 0.25 * h[selected]  (bf16 source)
// ---------------------------------------------------------------------------
__global__ void gather_bf16_add(const u16* __restrict__ h,
                                const int* __restrict__ users,
                                const int* __restrict__ items,
                                float* __restrict__ out) {
    int tid = blockIdx.x * blockDim.x + threadIdx.x;
    if (tid >= 2 * BATCH * (EMB / 4)) return;
    int b = tid >> 4;
    int e = (tid & 15) << 2;
    int row = (b < BATCH) ? users[b] : (items[b - BATCH] + USER_COUNT);
    ushort4 s = *(const ushort4*)(h + (size_t)row * EMB + e);
    float4* o = (float4*)(out + (size_t)b * EMB + e);
    float4 cur = *o;
    cur.x += 0.25f * bf2f(s.x);
    cur.y += 0.25f * bf2f(s.y);
    cur.z += 0.25f * bf2f(s.z);
    cur.w += 0.25f * bf2f(s.w);
    *o = cur;
}

extern "C" void kernel_launch(void* const* d_in, const int* in_sizes, int n_in,
                              void* d_out, int out_size, void* d_ws, size_t ws_size,
                              hipStream_t stream) {
    const float* user_emb = (const float*)d_in[0];
    const float* item_emb = (const float*)d_in[1];
    const int*   adj_row  = (const int*)d_in[2];
    const int*   adj_col  = (const int*)d_in[3];
    const float* adj_val  = (const float*)d_in[4];
    const int*   users    = (const int*)d_in[5];
    const int*   items    = (const int*)d_in[6];
    float*       out      = (float*)d_out;
    const int    nnz      = in_sizes[2];

    char* ws = (char*)d_ws;
    const size_t hbytes = (size_t)N_NODES * EMB * sizeof(u16); // 38.4 MB
    u16* ego16 = (u16*)(ws);
    u16* h1    = (u16*)(ws + hbytes);
    u16* h2    = (u16*)(ws + 2 * hbytes);
    int* ptr   = (int*)(ws + 3 * hbytes);

    // 1) row_ptr
    build_row_ptr<<<(nnz + 255) / 256, 256, 0, stream>>>(adj_row, ptr, nnz);

    // 2) ego -> bf16
    {
        const size_t total = (size_t)N_NODES * EMB / 4;
        convert_bf16<<<(unsigned)((total + 255) / 256), 256, 0, stream>>>(
            user_emb, item_emb, ego16);
    }

    // 3) out = 0.25 * ego[sel]  (exact f32)
    const int gthreads = 2 * BATCH * (EMB / 4);
    gather_f32<<<(gthreads + 255) / 256, 256, 0, stream>>>(
        user_emb, item_emb, users, items, out);

    const int spmm_blocks = (N_NODES + 3) / 4;

    // 4) h1 = A * ego16 ; out += 0.25*h1[sel]
    spmm_bf16<<<spmm_blocks, 256, 0, stream>>>(ego16, adj_col, adj_val, ptr, h1);
    gather_bf16_add<<<(gthreads + 255) / 256, 256, 0, stream>>>(h1, users, items, out);

    // 5) h2 = A * h1 ; out += 0.25*h2[sel]
    spmm_bf16<<<spmm_blocks, 256, 0, stream>>>(h1, adj_col, adj_val, ptr, h2);
    gather_bf16_add<<<(gthreads + 255) / 256, 256, 0, stream>>>(h2, users, items, out);

    // 6) out += 0.25 * (A*h2)[sel]   (layer 3 restricted to 8192 rows)
    spmm_bf16_sel<<<(2 * BATCH + 3) / 4, 256, 0, stream>>>(
        h2, adj_col, adj_val, ptr, users, items, out);
}

// Round 4
// 449.073 us; speedup vs baseline: 5.6855x; 1.1667x over previous
//
#include <hip/hip_runtime.h>

#define USER_COUNT 200000
#define ITEM_COUNT 100000
#define N_NODES    300000   // USER_COUNT + ITEM_COUNT
#define EMB        64
#define BATCH      4096

typedef unsigned int   u32;
typedef unsigned short u16;
typedef u16   ushort8v __attribute__((ext_vector_type(8)));
typedef float float8v  __attribute__((ext_vector_type(8)));

static __device__ __forceinline__ float bf2f(u16 h) {
    return __uint_as_float(((u32)h) << 16);
}
static __device__ __forceinline__ u16 f2bf(float f) {   // round-to-nearest-even
    u32 u = __float_as_uint(f);
    u32 r = (u + 0x7FFFu + ((u >> 16) & 1u)) >> 16;
    return (u16)r;
}

// ---------------------------------------------------------------------------
// row_ptr from sorted COO rows. ptr[r] = first i with row[i] >= r.
// ---------------------------------------------------------------------------
__global__ void build_row_ptr(const int* __restrict__ row,
                              int* __restrict__ ptr, int nnz) {
    int i = blockIdx.x * blockDim.x + threadIdx.x;
    if (i >= nnz) return;
    int r  = row[i];
    int rp = (i == 0) ? -1 : row[i - 1];
    for (int rr = rp + 1; rr <= r; ++rr) ptr[rr] = i;
    if (i == nnz - 1) {
        for (int rr = r + 1; rr <= N_NODES; ++rr) ptr[rr] = nnz;
    }
}

// ---------------------------------------------------------------------------
// ego16 = bf16(concat(user_emb, item_emb)); each thread converts 4 elems.
// ---------------------------------------------------------------------------
__global__ void convert_bf16(const float* __restrict__ ue,
                             const float* __restrict__ ie,
                             u16* __restrict__ out16) {
    size_t t = (size_t)blockIdx.x * blockDim.x + threadIdx.x;
    const size_t total = (size_t)N_NODES * EMB / 4;
    if (t >= total) return;
    size_t base = t * 4;
    const size_t ub = (size_t)USER_COUNT * EMB;
    const float* src = (base < ub) ? (ue + base) : (ie + (base - ub));
    float4 v = *(const float4*)src;
    ushort4 o;
    o.x = f2bf(v.x); o.y = f2bf(v.y); o.z = f2bf(v.z); o.w = f2bf(v.w);
    *(ushort4*)(out16 + base) = o;
}

// ---------------------------------------------------------------------------
// Inner gather-FMA: 8-lane group handles one edge; lane covers 8 bf16 dims
// (16 B load -> 1 KB per wave-wide vmem instruction across 8 edges).
// ---------------------------------------------------------------------------
#define EDGE_FMA8(J, ACC)                                             \
    {                                                                 \
        int   c = __builtin_nontemporal_load(col + (J));              \
        float v = __builtin_nontemporal_load(val + (J));              \
        ushort8v h8 = *(const ushort8v*)(x + (size_t)c * EMB + d);    \
        _Pragma("unroll")                                             \
        for (int q = 0; q < 8; ++q) ACC[q] += v * bf2f(h8[q]);        \
    }

#define SLOT_REDUCE(ACC)                                              \
    _Pragma("unroll")                                                 \
    for (int q = 0; q < 8; ++q) {                                     \
        ACC[q] += __shfl_xor(ACC[q], 8, 64);                          \
        ACC[q] += __shfl_xor(ACC[q], 16, 64);                         \
        ACC[q] += __shfl_xor(ACC[q], 32, 64);                         \
    }

// ---------------------------------------------------------------------------
// Full SpMM (bf16 in / bf16 out): one wave per row.
//   e = lane>>3 : edge slot (8 concurrent edges); d = (lane&7)*8 dims.
// Main loop unroll x2 (16 edges/iter in flight); tail stays 8-wide.
// ---------------------------------------------------------------------------
__global__ __launch_bounds__(256) void spmm_bf16(
        const u16* __restrict__ x, const int* __restrict__ col,
        const float* __restrict__ val, const int* __restrict__ ptr,
        u16* __restrict__ y) {
    int wave = (int)((blockIdx.x * blockDim.x + threadIdx.x) >> 6);
    int lane = threadIdx.x & 63;
    if (wave >= N_NODES) return;
    int e = lane >> 3;          // 0..7
    int d = (lane & 7) << 3;    // 0,8,...,56

    int p0 = ptr[wave];
    int p1 = ptr[wave + 1];

    float8v a0 = {0,0,0,0,0,0,0,0};
    float8v a1 = {0,0,0,0,0,0,0,0};

    int j = p0 + e;
    for (; j + 8 < p1; j += 16) {
        EDGE_FMA8(j,     a0);
        EDGE_FMA8(j + 8, a1);
    }
    if (j < p1) EDGE_FMA8(j, a0);

    #pragma unroll
    for (int q = 0; q < 8; ++q) a0[q] += a1[q];

    SLOT_REDUCE(a0);

    if (e == 0) {
        ushort8v o;
        #pragma unroll
        for (int q = 0; q < 8; ++q) o[q] = f2bf(a0[q]);
        *(ushort8v*)(y + (size_t)wave * EMB + d) = o;
    }
}

// ---------------------------------------------------------------------------
// Layer-3 SpMM restricted to the 8192 selected rows, fused with output
// accumulation: out[slot] += 0.25 * (A * x)[row(slot)].
// ---------------------------------------------------------------------------
__global__ __launch_bounds__(256) void spmm_bf16_sel(
        const u16* __restrict__ x, const int* __restrict__ col,
        const float* __restrict__ val, const int* __restrict__ ptr,
        const int* __restrict__ users, const int* __restrict__ items,
        float* __restrict__ out) {
    int slot = (int)((blockIdx.x * blockDim.x + threadIdx.x) >> 6);
    if (slot >= 2 * BATCH) return;
    int lane = threadIdx.x & 63;
    int e = lane >> 3;
    int d = (lane & 7) << 3;

    int row = (slot < BATCH) ? users[slot] : (items[slot - BATCH] + USER_COUNT);
    int p0 = ptr[row];
    int p1 = ptr[row + 1];

    float8v a0 = {0,0,0,0,0,0,0,0};
    float8v a1 = {0,0,0,0,0,0,0,0};

    int j = p0 + e;
    for (; j + 8 < p1; j += 16) {
        EDGE_FMA8(j,     a0);
        EDGE_FMA8(j + 8, a1);
    }
    if (j < p1) EDGE_FMA8(j, a0);

    #pragma unroll
    for (int q = 0; q < 8; ++q) a0[q] += a1[q];

    SLOT_REDUCE(a0);

    if (e == 0) {
        float* o = out + (size_t)slot * EMB + d;
        float4 c0 = *(float4*)o;
        float4 c1 = *(float4*)(o + 4);
        c0.x += 0.25f * a0[0]; c0.y += 0.25f * a0[1];
        c0.z += 0.25f * a0[2]; c0.w += 0.25f * a0[3];
        c1.x += 0.25f * a0[4]; c1.y += 0.25f * a0[5];
        c1.z += 0.25f * a0[6]; c1.w += 0.25f * a0[7];
        *(float4*)o       = c0;
        *(float4*)(o + 4) = c1;
    }
}

// ---------------------------------------------------------------------------
// out = 0.25 * ego[selected]  (exact f32 inputs; first write)
// ---------------------------------------------------------------------------
__global__ void gather_f32(const float* __restrict__ xu,
                           const float* __restrict__ xi,
                           const int* __restrict__ users,
                           const int* __restrict__ items,
                           float* __restrict__ out) {
    int tid = blockIdx.x * blockDim.x + threadIdx.x;
    if (tid >= 2 * BATCH * (EMB / 4)) return;
    int b = tid >> 4;
    int e = (tid & 15) << 2;
    const float* src;
    if (b < BATCH) src = xu + (size_t)users[b] * EMB + e;
    else           src = xi + (size_t)items[b - BATCH] * EMB + e;
    float4 s = *(const float4*)src;
    float4 v = {0.25f * s.x, 0.25f * s.y, 0.25f * s.z, 0.25f * s.w};
    *(float4*)(out + (size_t)b * EMB + e) = v;
}

// ---------------------------------------------------------------------------
// out += 0.25 * h[selected]  (bf16 source)
// ---------------------------------------------------------------------------
__global__ void gather_bf16_add(const u16* __restrict__ h,
                                const int* __restrict__ users,
                                const int* __restrict__ items,
                                float* __restrict__ out) {
    int tid = blockIdx.x * blockDim.x + threadIdx.x;
    if (tid >= 2 * BATCH * (EMB / 4)) return;
    int b = tid >> 4;
    int e = (tid & 15) << 2;
    int row = (b < BATCH) ? users[b] : (items[b - BATCH] + USER_COUNT);
    ushort4 s = *(const ushort4*)(h + (size_t)row * EMB + e);
    float4* o = (float4*)(out + (size_t)b * EMB + e);
    float4 cur = *o;
    cur.x += 0.25f * bf2f(s.x);
    cur.y += 0.25f * bf2f(s.y);
    cur.z += 0.25f * bf2f(s.z);
    cur.w += 0.25f * bf2f(s.w);
    *o = cur;
}

extern "C" void kernel_launch(void* const* d_in, const int* in_sizes, int n_in,
                              void* d_out, int out_size, void* d_ws, size_t ws_size,
                              hipStream_t stream) {
    const float* user_emb = (const float*)d_in[0];
    const float* item_emb = (const float*)d_in[1];
    const int*   adj_row  = (const int*)d_in[2];
    const int*   adj_col  = (const int*)d_in[3];
    const float* adj_val  = (const float*)d_in[4];
    const int*   users    = (const int*)d_in[5];
    const int*   items    = (const int*)d_in[6];
    float*       out      = (float*)d_out;
    const int    nnz      = in_sizes[2];

    char* ws = (char*)d_ws;
    const size_t hbytes = (size_t)N_NODES * EMB * sizeof(u16); // 38.4 MB
    u16* ego16 = (u16*)(ws);
    u16* h1    = (u16*)(ws + hbytes);
    u16* h2    = (u16*)(ws + 2 * hbytes);
    int* ptr   = (int*)(ws + 3 * hbytes);

    // 1) row_ptr
    build_row_ptr<<<(nnz + 255) / 256, 256, 0, stream>>>(adj_row, ptr, nnz);

    // 2) ego -> bf16
    {
        const size_t total = (size_t)N_NODES * EMB / 4;
        convert_bf16<<<(unsigned)((total + 255) / 256), 256, 0, stream>>>(
            user_emb, item_emb, ego16);
    }

    // 3) out = 0.25 * ego[sel]  (exact f32)
    const int gthreads = 2 * BATCH * (EMB / 4);
    gather_f32<<<(gthreads + 255) / 256, 256, 0, stream>>>(
        user_emb, item_emb, users, items, out);

    const int spmm_blocks = (N_NODES + 3) / 4;

    // 4) h1 = A * ego16 ; out += 0.25*h1[sel]
    spmm_bf16<<<spmm_blocks, 256, 0, stream>>>(ego16, adj_col, adj_val, ptr, h1);
    gather_bf16_add<<<(gthreads + 255) / 256, 256, 0, stream>>>(h1, users, items, out);

    // 5) h2 = A * h1 ; out += 0.25*h2[sel]
    spmm_bf16<<<spmm_blocks, 256, 0, stream>>>(h1, adj_col, adj_val, ptr, h2);
    gather_bf16_add<<<(gthreads + 255) / 256, 256, 0, stream>>>(h2, users, items, out);

    // 6) out += 0.25 * (A*h2)[sel]   (layer 3 restricted to 8192 rows)
    spmm_bf16_sel<<<(2 * BATCH + 3) / 4, 256, 0, stream>>>(
        h2, adj_col, adj_val, ptr, users, items, out);
}